// Round 10
// baseline (208.013 us; speedup 1.0000x reference)
//
#include <hip/hip_runtime.h>
#include <stdint.h>

typedef unsigned int u32;
typedef unsigned long long u64;

#define N8   130560   // (2176/8)*(3840/8)   = 272*480
#define N16  32640    // (2176/16)*(3840/16) = 136*240
#define N32  8160     // (2176/32)*(3840/32) = 68*120
#define NTOT 171360
#define NTOT4 42840   // NTOT/4
#define TOPK 1000
#define NWORDS 16     // rank-space nz bitmap words
#define CWORDS 32     // candidate-space rem words (2016 bits)
#define NBINS 512
#define BUCKET_SCALE 85.25f
#define LIST_CAP 2016      // 63*32
#define CPB 32             // candidates per k5 block
#define HIST_BLKS 84       // 84*512 threads = 43008 >= NTOT4
#define HIST_THR 512
#define CMP_BLKS 168       // ceil(NTOT4/256)
#define K5_BLKS 63
#define NMS_CACHE 192

// R18: 4 -> 3 dispatches. IOU moves from k67 into k5 in CANDIDATE space:
// rank order is encoded in the keys k5 already holds (rank_j > rank_c <=>
// keys[j] < keys[c]), so each block computes mask rows for its own ranked
// candidates vs all 2016 columns using cboxes[] decoded once by k4. Extra
// column bits (rank>=1000 candidates) are never read -> semantics identical
// to the reference 1000x1000 matrix. NMS = k5's last-arriver tail (proven
// pattern): rem = 32 candidate-space words over 32 lanes, chain iterates
// rank-ordered nonzero rows via a rank->cand map. k67 eliminated.
// R14/R17 lessons kept: redundant parallel findB, no spins, plain-cached
// cross-dispatch data, sc1 only for same-dispatch handoffs.

#define MI_CNT 0       // line 0: k4 list-count RMW (zeroed by k1 blk0)
#define MI_K5  128     // line 1: k5 arrive ctr    (zeroed by k1 blk0)
#define META_U32 256

// workspace layout (bytes)
#define OFF_PART 0                  // u32[84*256] u16-pair packed partial hist
#define OFF_META 86016              // u32[256]
#define OFF_NZ   87040              // u64[16]  rank-space nz bitmap
#define OFF_LIST 87168              // u64[2016]
#define OFF_CBOX 103296             // float4[2016] candidate boxes (k4 -> k5)
#define OFF_R2C  135552             // u32[1000] rank -> candidate map
#define OFF_MASK 139552             // u64[32*1000] transposed: mask[w*1000+r]

__device__ __forceinline__ u32 ald32(const u32* p) {
  return __hip_atomic_load(p, __ATOMIC_RELAXED, __HIP_MEMORY_SCOPE_AGENT);
}
__device__ __forceinline__ u64 ald64(const u64* p) {
  return __hip_atomic_load(p, __ATOMIC_RELAXED, __HIP_MEMORY_SCOPE_AGENT);
}
__device__ __forceinline__ void ast32(u32* p, u32 v) {
  __hip_atomic_store(p, v, __ATOMIC_RELAXED, __HIP_MEMORY_SCOPE_AGENT);
}
__device__ __forceinline__ void ast64(u64* p, u64 v) {
  __hip_atomic_store(p, v, __ATOMIC_RELAXED, __HIP_MEMORY_SCOPE_AGENT);
}

__device__ __forceinline__ u32 bucket_of(float x) {
  u32 b = (u32)(x * BUCKET_SCALE);
  return b > (NBINS - 1) ? (NBINS - 1) : b;
}

__device__ __forceinline__ float4 load_logit4(int v, const float* s8, const float* s16,
                                              const float* s32) {
  int e = v * 4;
  if (e < N8) return ((const float4*)s8)[v];
  if (e < N8 + N16) return ((const float4*)s16)[v - N8 / 4];
  return ((const float4*)s32)[v - (N8 + N16) / 4];
}

__device__ __forceinline__ bool iou_gt04(float4 a, float4 b) {
#pragma clang fp contract(off)
  float areaA = (a.z - a.x) * (a.w - a.y);
  float areaB = (b.z - b.x) * (b.w - b.y);
  float ltx = fmaxf(a.x, b.x);
  float lty = fmaxf(a.y, b.y);
  float rbx = fminf(a.z, b.z);
  float rby = fminf(a.w, b.w);
  float wx = rbx - ltx; wx = wx > 0.0f ? wx : 0.0f;
  float wy = rby - lty; wy = wy > 0.0f ? wy : 0.0f;
  float inter = wx * wy;
  float un = areaA + areaB - inter;
  un = un > 1e-9f ? un : 1e-9f;
  return (inter / un) > 0.4f;
}

__device__ __forceinline__ u64 valid_word(int w, u32 vcnt) {
  int lo = w * 64;
  if ((int)vcnt >= lo + 64) return ~0ull;
  if ((int)vcnt <= lo) return 0ull;
  return (1ull << (vcnt - (u32)lo)) - 1ull;
}

// decode helper: candidate idx -> level params
__device__ __forceinline__ void level_of(u32 idx, int& p, int& xq, int& yq, float& st,
                                         int& lvl) {
  if (idx < N8) {
    st = 8.f;  p = (int)idx;              xq = p % 480; yq = p / 480; lvl = 0;
  } else if (idx < N8 + N16) {
    st = 16.f; p = (int)idx - N8;         xq = p % 240; yq = p / 240; lvl = 1;
  } else {
    st = 32.f; p = (int)idx - (N8 + N16); xq = p % 120; yq = p / 120; lvl = 2;
  }
}

// K1: pure histogram. 84x512, LDS 512-bin hist -> u16-packed partial (plain).
// blk0 zeroes meta + rank-space nz bitmap.
__global__ void __launch_bounds__(HIST_THR) k1_hist(
    const float* __restrict__ s8, const float* __restrict__ s16, const float* __restrict__ s32,
    u32* __restrict__ part, u32* __restrict__ meta, u64* __restrict__ nz) {
  __shared__ u32 lh[NBINS];
  const int t = threadIdx.x, blk = blockIdx.x;
  if (t < NBINS) lh[t] = 0;       // HIST_THR == 512 == NBINS
  __syncthreads();
  int v = blk * HIST_THR + t;
  if (v < NTOT4) {
    float4 x = load_logit4(v, s8, s16, s32);
    if (x.x > 0.0f) atomicAdd(&lh[bucket_of(x.x)], 1u);
    if (x.y > 0.0f) atomicAdd(&lh[bucket_of(x.y)], 1u);
    if (x.z > 0.0f) atomicAdd(&lh[bucket_of(x.z)], 1u);
    if (x.w > 0.0f) atomicAdd(&lh[bucket_of(x.w)], 1u);
  }
  __syncthreads();
  if (t < 256)                    // per-block bin count <= 2048 -> u16 ok
    part[blk * 256 + t] = lh[2 * t] | (lh[2 * t + 1] << 16);
  if (blk == 0) {
    if (t < META_U32) meta[t] = 0;
    if (t < NWORDS) nz[t] = 0ull;
  }
}

// K4: redundant parallel findB + block-aggregated compaction + box decode.
__global__ void __launch_bounds__(256) k4_compact(
    const float* __restrict__ s8, const float* __restrict__ s16, const float* __restrict__ s32,
    const float* __restrict__ bb8, const float* __restrict__ bb16, const float* __restrict__ bb32,
    const u32* __restrict__ part, u32* __restrict__ meta, u64* __restrict__ list,
    float4* __restrict__ cbox) {
  __shared__ u32 csum[256];
  __shared__ u32 sB, sBase;
  __shared__ u32 cnt16[16];
  const int t = threadIdx.x, blk = blockIdx.x;
  const int wave = t >> 6, lane = t & 63;
  const int v = blk * 256 + t;
  float4 x = make_float4(-1.f, -1.f, -1.f, -1.f);
  if (v < NTOT4) x = load_logit4(v, s8, s16, s32);

  // ---- redundant findB: thread t owns packed word t (bins 2t, 2t+1) ----
  u32 lo = 0, hi = 0;
  {
    int p = 0;
    for (; p + 4 <= HIST_BLKS; p += 4) {
      u32 a0 = part[(p + 0) * 256 + t];
      u32 a1 = part[(p + 1) * 256 + t];
      u32 a2 = part[(p + 2) * 256 + t];
      u32 a3 = part[(p + 3) * 256 + t];
      lo += (a0 & 0xFFFFu) + (a1 & 0xFFFFu) + (a2 & 0xFFFFu) + (a3 & 0xFFFFu);
      hi += (a0 >> 16) + (a1 >> 16) + (a2 >> 16) + (a3 >> 16);
    }
    for (; p < HIST_BLKS; ++p) {
      u32 a = part[p * 256 + t];
      lo += a & 0xFFFFu; hi += a >> 16;
    }
  }
  csum[t] = lo + hi;
  __syncthreads();
  for (int off = 1; off < 256; off <<= 1) {   // inclusive suffix scan over words
    u32 add = (t + off < 256) ? csum[t + off] : 0u;
    __syncthreads();
    csum[t] += add;
    __syncthreads();
  }
  u32 above = (t < 255) ? csum[t + 1] : 0u;
  if (t == 0 && csum[0] < TOPK) sB = 0u;
  if (csum[t] >= TOPK && above < TOPK)
    sB = (above + hi >= TOPK) ? (u32)(2 * t + 1) : (u32)(2 * t);
  __syncthreads();

  // ---- compact + box decode ----
  const u32 B = sB;
  float c[4] = {x.x, x.y, x.z, x.w};
  u32 win = 0;
#pragma unroll
  for (int j = 0; j < 4; ++j)
    if (c[j] > 0.0f && bucket_of(c[j]) >= B) win |= 1u << j;
  u32 wpos[4], wcnt[4];
#pragma unroll
  for (int j = 0; j < 4; ++j) {
    u64 bal = __ballot((win >> j) & 1u);
    wcnt[j] = (u32)__popcll(bal);
    wpos[j] = (u32)__popcll(bal & ((1ull << lane) - 1ull));
  }
  if (lane == 0) {
#pragma unroll
    for (int j = 0; j < 4; ++j) cnt16[wave * 4 + j] = wcnt[j];
  }
  __syncthreads();
  if (t == 0) {
    u32 tot = 0, pre[16];
#pragma unroll
    for (int k = 0; k < 16; ++k) { pre[k] = tot; tot += cnt16[k]; }
#pragma unroll
    for (int k = 0; k < 16; ++k) cnt16[k] = pre[k];
    sBase = tot ? atomicAdd(&meta[MI_CNT], tot) : 0u;
  }
  __syncthreads();
#pragma unroll
  for (int j = 0; j < 4; ++j) {
    if ((win >> j) & 1u) {
      u32 dst = sBase + cnt16[wave * 4 + j] + wpos[j];
      if (dst < LIST_CAP) {
        u32 idx = (u32)(v * 4 + j);
        list[dst] = ((u64)__float_as_uint(c[j]) << 32) | (u64)(~idx);
        int p, xq, yq, lvl;
        float st;
        level_of(idx, p, xq, yq, st, lvl);
        const float* bb = (lvl == 0) ? bb8 : (lvl == 1) ? bb16 : bb32;
        float4 d = ((const float4*)bb)[p];
        float cx = (float)xq * st, cy = (float)yq * st;
        float4 box;
        {
#pragma clang fp contract(off)
          box.x = cx - d.x * st; box.y = cy - d.y * st;
          box.z = cx + d.z * st; box.w = cy + d.w * st;
        }
        cbox[dst] = box;                 // plain: k4->k5 crosses a boundary
      }
    }
  }
}

// K5: rank + decode + candidate-space IOU + last-arriver NMS + zeroing.
__global__ void __launch_bounds__(256) k5_all(
    u32* meta, const u64* __restrict__ list, const float4* __restrict__ cbox_g,
    const float* __restrict__ kp8, const float* __restrict__ kp16,
    const float* __restrict__ kp32,
    u64* nzr, u64* mask, u32* r2c_g, float* out) {
  __shared__ __align__(16) char smem[57344];
  __shared__ u32 rpart[256];
  __shared__ u32 rankOf[CPB];
  __shared__ u64 rownz[CPB * 8];
  __shared__ u32 sCnt;
  __shared__ int isLast;
  __shared__ u32 sPc[NWORDS], sOff17[NWORDS + 1];
  __shared__ u64 sRem32[CWORDS];
  const int t = threadIdx.x, blk = blockIdx.x;
  u64* o64 = (u64*)out;

  u64* keys = (u64*)smem;                        // [2016] = 16128 B
  float4* cbox = (float4*)(smem + 16384);        // [2016] = 32256 B (-> 48640)

  if (t == 0) { u32 cc = meta[MI_CNT]; sCnt = cc > LIST_CAP ? LIST_CAP : cc; }
  __syncthreads();
  const u32 cnt = sCnt;
  for (int j = t; j < LIST_CAP; j += 256) {
    keys[j] = (j < (int)cnt) ? list[j] : 0ull;
    cbox[j] = (j < (int)cnt) ? cbox_g[j] : make_float4(0.f, 0.f, 0.f, 0.f);
  }
  __syncthreads();

  // ---- rank (8 key-slices per candidate) ----
  {
    const int ci = t & 31, sl = t >> 5;
    const int c = blk * CPB + ci;
    const int chunk = ((int)cnt + 7) >> 3;
    int lo = sl * chunk; if (lo > (int)cnt) lo = (int)cnt;
    int hi = lo + chunk; if (hi > (int)cnt) hi = (int)cnt;
    u64 my = keys[c];
    int r = 0, j = lo;
    for (; j + 4 <= hi; j += 4)
      r += (keys[j] > my) + (keys[j + 1] > my) + (keys[j + 2] > my) + (keys[j + 3] > my);
    for (; j < hi; ++j) r += (keys[j] > my);
    rpart[t] = (u32)r;
  }
  __syncthreads();

  // ---- decode + out writes (sc1: shared lines with last-arriver zeroing) ----
  if (t < CPB) {
    const int c = blk * CPB + t;
    u32 rk = 0xFFFFFFFFu;
    if (c < (int)cnt) {
      int rank = 0;
#pragma unroll
      for (int q = 0; q < 8; ++q) rank += (int)rpart[t + 32 * q];
      if (rank < TOPK) {
        rk = (u32)rank;
        u64 my = keys[c];
        float lx = __uint_as_float((u32)(my >> 32));
        float sc = (float)(1.0 / (1.0 + exp(-(double)lx)));   // f64 sigmoid, round once
        u32 idx = ~((u32)my);
        int p, xq, yq, lvl;
        float st;
        level_of(idx, p, xq, yq, st, lvl);
        const float* kp = (lvl == 0) ? kp8 : (lvl == 1) ? kp16 : kp32;
        float cx = (float)xq * st, cy = (float)yq * st;
        float kv[10];
        {
#pragma clang fp contract(off)
          for (int q = 0; q < 10; ++q)
            kv[q] = kp[10 * p + q] * st + ((q & 1) ? cy : cx);
        }
        float4 box = cbox[c];
        ast64(&o64[2 * rank],     ((u64)__float_as_uint(box.y) << 32) | __float_as_uint(box.x));
        ast64(&o64[2 * rank + 1], ((u64)__float_as_uint(box.w) << 32) | __float_as_uint(box.z));
        ast32(&((u32*)out)[4000 + rank], __float_as_uint(sc));
        int wb = 2500 + 5 * rank;
#pragma unroll
        for (int q = 0; q < 5; ++q)
          ast64(&o64[wb + q],
                ((u64)__float_as_uint(kv[2 * q + 1]) << 32) | __float_as_uint(kv[2 * q]));
        ast32(&r2c_g[rank], (u32)c);             // rank -> candidate map
      }
    } else if (c < TOPK) {                       // unfilled rows: zero once
      ast64(&o64[2 * c], 0ull); ast64(&o64[2 * c + 1], 0ull);
      ast32(&((u32*)out)[4000 + c], 0u);
      int wb = 2500 + 5 * c;
#pragma unroll
      for (int q = 0; q < 5; ++q) ast64(&o64[wb + q], 0ull);
    }
    rankOf[t] = rk;
  }
  __syncthreads();

  // ---- candidate-space IOU: row ci (8 col-slices), cols candidate-indexed ----
  {
    const int ci = t & 31, sl = t >> 5;
    const u32 r = rankOf[ci];
    u64 w0 = 0, w1 = 0, w2 = 0, w3 = 0;
    if (r != 0xFFFFFFFFu) {
      const int c = blk * CPB + ci;
      const u64 myKey = keys[c];
      const float4 a = cbox[c];
      const int j0 = sl * 256;
      const int jend = (j0 + 256 < LIST_CAP) ? 256 : (LIST_CAP - j0);
      for (int jj = 0; jj < jend; ++jj) {
        const int j = j0 + jj;                   // keys[j] wave-broadcast (32 lanes share j)
        if (keys[j] < myKey && iou_gt04(a, cbox[j])) {
          u64 bit = 1ull << (jj & 63);
          if (jj < 64) w0 |= bit; else if (jj < 128) w1 |= bit;
          else if (jj < 192) w2 |= bit; else w3 |= bit;
        }
      }
      const int wbase = sl * 4;
      ast64(&mask[(u64)(wbase + 0) * 1000 + r], w0);
      ast64(&mask[(u64)(wbase + 1) * 1000 + r], w1);
      ast64(&mask[(u64)(wbase + 2) * 1000 + r], w2);
      ast64(&mask[(u64)(wbase + 3) * 1000 + r], w3);
    }
    rownz[ci * 8 + sl] = w0 | w1 | w2 | w3;
  }
  __syncthreads();
  if (t < CPB) {
    const u32 r = rankOf[t];
    u64 nzrow = rownz[t * 8 + 0] | rownz[t * 8 + 1] | rownz[t * 8 + 2] | rownz[t * 8 + 3]
              | rownz[t * 8 + 4] | rownz[t * 8 + 5] | rownz[t * 8 + 6] | rownz[t * 8 + 7];
    if (r != 0xFFFFFFFFu && nzrow)
      atomicOr(&nzr[r >> 6], 1ull << (r & 63));
  }
  __syncthreads();                               // drain sc1 stores + RMWs (vmcnt)
  if (t == 0)
    isLast = (__hip_atomic_fetch_add(&meta[MI_K5], 1u, __ATOMIC_RELAXED,
                                     __HIP_MEMORY_SCOPE_AGENT) == (u32)(K5_BLKS - 1));
  __syncthreads();
  if (!isLast) return;

  // ---- last arriver: greedy NMS over nonzero ranked rows ----
  const u32 vcnt = cnt < TOPK ? cnt : TOPK;
  u32* rows = (u32*)smem;                        // [1000] @0
  u32* r2cL = (u32*)(smem + 4096);               // [1000]
  u64* cache = (u64*)(smem + 8192);              // [192][32] = 49152 B
  u64 nzv = 0;
  if (t < NWORDS) {
    nzv = ald64(&nzr[t]) & valid_word(t, vcnt);
    sPc[t] = (u32)__popcll(nzv);
  }
  for (int r = t; r < TOPK; r += 256)
    r2cL[r] = (r < (int)vcnt) ? ald32(&r2c_g[r]) : 0u;
  __syncthreads();
  if (t == 0) {
    u32 o = 0;
    for (int w = 0; w < NWORDS; ++w) { sOff17[w] = o; o += sPc[w]; }
    sOff17[NWORDS] = o;
  }
  __syncthreads();
  if (t < NWORDS) {                              // ascending rank order
    u64 m = nzv;
    u32 o = sOff17[t];
    while (m) { int b = __builtin_ctzll(m); m &= m - 1; rows[o++] = (u32)(t * 64 + b); }
  }
  __syncthreads();
  const int S = (int)sOff17[NWORDS];
  const int Sc = S < NMS_CACHE ? S : NMS_CACHE;
  for (int idx = t; idx < Sc * CWORDS; idx += 256) {   // parallel mask prefetch
    int s = idx >> 5, w = idx & 31;
    cache[s * CWORDS + w] = ald64(&mask[(u64)w * 1000 + rows[s]]);
  }
  __syncthreads();
  if (t < 64) {                 // serial greedy chain; lanes 0..31 own rem words
    u64 remv = 0;
    for (int s = 0; s < S; ++s) {
      u32 r = rows[s];
      u32 c = r2cL[r];
      int cl = (int)(c >> 6), cb = (int)(c & 63);
      u64 remc = __shfl(remv, cl);
      if (!((remc >> cb) & 1ull)) {      // row alive -> apply its suppression row
        u64 m = 0;
        if (t < CWORDS)
          m = (s < NMS_CACHE) ? cache[s * CWORDS + t] : ald64(&mask[(u64)t * 1000 + r]);
        remv |= m;
      }
    }
    if (t < CWORDS) sRem32[t] = remv;
  }
  __syncthreads();
  for (int r = t; r < TOPK; r += 256) {
    if (r < (int)vcnt) {
      u32 c = r2cL[r];
      if ((sRem32[c >> 6] >> (c & 63)) & 1ull) {
        ast64(&o64[2 * r], 0ull); ast64(&o64[2 * r + 1], 0ull);
        ast32(&((u32*)out)[4000 + r], 0u);
        int wb = 2500 + 5 * r;
#pragma unroll
        for (int q = 0; q < 5; ++q) ast64(&o64[wb + q], 0ull);
      }
    }
  }
}

extern "C" void kernel_launch(void* const* d_in, const int* in_sizes, int n_in,
                              void* d_out, int out_size, void* d_ws, size_t ws_size,
                              hipStream_t stream) {
  const float* s8   = (const float*)d_in[1];
  const float* bb8  = (const float*)d_in[2];
  const float* kp8  = (const float*)d_in[3];
  const float* s16  = (const float*)d_in[4];
  const float* bb16 = (const float*)d_in[5];
  const float* kp16 = (const float*)d_in[6];
  const float* s32  = (const float*)d_in[7];
  const float* bb32 = (const float*)d_in[8];
  const float* kp32 = (const float*)d_in[9];

  char* ws = (char*)d_ws;
  u32* part    = (u32*)(ws + OFF_PART);
  u32* meta    = (u32*)(ws + OFF_META);
  u64* nzr     = (u64*)(ws + OFF_NZ);
  u64* list    = (u64*)(ws + OFF_LIST);
  float4* cbox = (float4*)(ws + OFF_CBOX);
  u32* r2c     = (u32*)(ws + OFF_R2C);
  u64* mask    = (u64*)(ws + OFF_MASK);
  float* out   = (float*)d_out;

  k1_hist<<<HIST_BLKS, HIST_THR, 0, stream>>>(s8, s16, s32, part, meta, nzr);
  k4_compact<<<CMP_BLKS, 256, 0, stream>>>(s8, s16, s32, bb8, bb16, bb32,
                                           part, meta, list, cbox);
  k5_all<<<K5_BLKS, 256, 0, stream>>>(meta, list, cbox, kp8, kp16, kp32,
                                      nzr, mask, r2c, out);
}

// Round 11
// 167.343 us; speedup vs baseline: 1.2430x; 1.2430x over previous
//
#include <hip/hip_runtime.h>
#include <stdint.h>

typedef unsigned int u32;
typedef unsigned long long u64;

#define N8   130560   // (2176/8)*(3840/8)   = 272*480
#define N16  32640    // (2176/16)*(3840/16) = 136*240
#define N32  8160     // (2176/32)*(3840/32) = 68*120
#define NTOT 171360
#define NTOT4 42840   // NTOT/4
#define TOPK 1000
#define NWORDS 16
#define NBINS 512
#define BUCKET_SCALE 85.25f
#define LIST_CAP 2016      // 63*32
#define CPB 32             // candidates ranked per block
#define HIST_BLKS 42       // R19: 42 x 1024 thr = 43008 >= NTOT4 (same 672 waves)
#define HIST_THR 1024
#define CMP_BLKS 168       // ceil(NTOT4/256)
#define RANK_BLKS 63
#define IOU_BLKS 63
#define IOU_TASKS (TOPK * NWORDS)   // 16000
#define NMS_CACHE 256

// R19: revert to R17 (166.6us best) after R18's candidate-space IOU blew up
// (4M evals @ 256/thread on 63 low-occupancy blocks = 62us kernel; lesson:
// arithmetic-check eval-count x serial-length before relocating work).
// One low-risk trim vs R17: k1 = 42 blocks x 1024 threads (SAME wave count —
// R16's regression was halved waves, not block shape; per-block bin counts
// <= 4096 still fit u16), so k4's redundant findB reduce halves (42 partials,
// 43KB). Everything else identical to R17: 4 dispatches, zero spins, redundant
// parallel findB in k4, rank-space IOU in k67 + last-arriver NMS.

#define MI_CNT 0       // line 0: k4 list-count RMW (zeroed by k1 blk0)
#define MI_IOU 128     // line 1: k67 arrive ctr   (zeroed by k1 blk0)
#define META_U32 256

// workspace layout (bytes)
#define OFF_PART 0                  // u32[42*256] u16-pair packed partial hist
#define OFF_META 43008              // u32[256]
#define OFF_NZ   44032              // u64[16]
#define OFF_LIST 44160              // u64[2016]
#define OFF_MASK 60288              // u64[16*1000] transposed: mask[w*1000+i]

__device__ __forceinline__ u64 ald64(const u64* p) {
  return __hip_atomic_load(p, __ATOMIC_RELAXED, __HIP_MEMORY_SCOPE_AGENT);
}
__device__ __forceinline__ void ast64(u64* p, u64 v) {
  __hip_atomic_store(p, v, __ATOMIC_RELAXED, __HIP_MEMORY_SCOPE_AGENT);
}

__device__ __forceinline__ u32 bucket_of(float x) {
  u32 b = (u32)(x * BUCKET_SCALE);
  return b > (NBINS - 1) ? (NBINS - 1) : b;
}

__device__ __forceinline__ float4 load_logit4(int v, const float* s8, const float* s16,
                                              const float* s32) {
  int e = v * 4;
  if (e < N8) return ((const float4*)s8)[v];
  if (e < N8 + N16) return ((const float4*)s16)[v - N8 / 4];
  return ((const float4*)s32)[v - (N8 + N16) / 4];
}

__device__ __forceinline__ bool iou_gt04(float4 a, float4 b) {
#pragma clang fp contract(off)
  float areaA = (a.z - a.x) * (a.w - a.y);
  float areaB = (b.z - b.x) * (b.w - b.y);
  float ltx = fmaxf(a.x, b.x);
  float lty = fmaxf(a.y, b.y);
  float rbx = fminf(a.z, b.z);
  float rby = fminf(a.w, b.w);
  float wx = rbx - ltx; wx = wx > 0.0f ? wx : 0.0f;
  float wy = rby - lty; wy = wy > 0.0f ? wy : 0.0f;
  float inter = wx * wy;
  float un = areaA + areaB - inter;
  un = un > 1e-9f ? un : 1e-9f;
  return (inter / un) > 0.4f;
}

__device__ __forceinline__ u64 valid_word(int w, u32 vcnt) {
  int lo = w * 64;
  if ((int)vcnt >= lo + 64) return ~0ull;
  if ((int)vcnt <= lo) return 0ull;
  return (1ull << (vcnt - (u32)lo)) - 1ull;
}

// K1: pure histogram. 42x1024, LDS 512-bin hist -> u16-packed partial (PLAIN
// stores; dispatch boundary provides coherence). blk0 zeroes meta + nz.
__global__ void __launch_bounds__(HIST_THR) k1_hist(
    const float* __restrict__ s8, const float* __restrict__ s16, const float* __restrict__ s32,
    u32* __restrict__ part, u32* __restrict__ meta, u64* __restrict__ nz) {
  __shared__ u32 lh[NBINS];
  const int t = threadIdx.x, blk = blockIdx.x;
  if (t < NBINS) lh[t] = 0;
  __syncthreads();
  int v = blk * HIST_THR + t;
  if (v < NTOT4) {
    float4 x = load_logit4(v, s8, s16, s32);
    if (x.x > 0.0f) atomicAdd(&lh[bucket_of(x.x)], 1u);
    if (x.y > 0.0f) atomicAdd(&lh[bucket_of(x.y)], 1u);
    if (x.z > 0.0f) atomicAdd(&lh[bucket_of(x.z)], 1u);
    if (x.w > 0.0f) atomicAdd(&lh[bucket_of(x.w)], 1u);
  }
  __syncthreads();
  if (t < 256)                    // per-block bin count <= 4096 -> u16 ok
    part[blk * 256 + t] = lh[2 * t] | (lh[2 * t + 1] << 16);
  if (blk == 0) {
    if (t < META_U32) meta[t] = 0;
    if (t < NWORDS) nz[t] = 0ull;
  }
}

// K4: every block: redundant parallel findB (reduce 42 partials + 256-word scan)
// then block-aggregated compaction. Plain cached loads; one atomicAdd per block.
__global__ void __launch_bounds__(256) k4_compact(
    const float* __restrict__ s8, const float* __restrict__ s16, const float* __restrict__ s32,
    const u32* __restrict__ part, u32* __restrict__ meta, u64* __restrict__ list) {
  __shared__ u32 csum[256];
  __shared__ u32 sB, sBase;
  __shared__ u32 cnt16[16];
  const int t = threadIdx.x, blk = blockIdx.x;
  const int wave = t >> 6, lane = t & 63;
  const int v = blk * 256 + t;
  // prefetch scores early (latency overlap with the reduce below)
  float4 x = make_float4(-1.f, -1.f, -1.f, -1.f);
  if (v < NTOT4) x = load_logit4(v, s8, s16, s32);

  // ---- redundant findB: thread t owns packed word t (bins 2t, 2t+1) ----
  u32 lo = 0, hi = 0;
  {
    int p = 0;
    for (; p + 4 <= HIST_BLKS; p += 4) {    // coalesced across threads at each p
      u32 a0 = part[(p + 0) * 256 + t];
      u32 a1 = part[(p + 1) * 256 + t];
      u32 a2 = part[(p + 2) * 256 + t];
      u32 a3 = part[(p + 3) * 256 + t];
      lo += (a0 & 0xFFFFu) + (a1 & 0xFFFFu) + (a2 & 0xFFFFu) + (a3 & 0xFFFFu);
      hi += (a0 >> 16) + (a1 >> 16) + (a2 >> 16) + (a3 >> 16);
    }
    for (; p < HIST_BLKS; ++p) {
      u32 a = part[p * 256 + t];
      lo += a & 0xFFFFu; hi += a >> 16;
    }
  }
  csum[t] = lo + hi;
  __syncthreads();
  for (int off = 1; off < 256; off <<= 1) {   // inclusive suffix scan over words
    u32 add = (t + off < 256) ? csum[t + off] : 0u;
    __syncthreads();
    csum[t] += add;
    __syncthreads();
  }
  u32 above = (t < 255) ? csum[t + 1] : 0u;
  if (t == 0 && csum[0] < TOPK) sB = 0u;      // fewer than TOPK positives
  if (csum[t] >= TOPK && above < TOPK)        // exactly one thread
    sB = (above + hi >= TOPK) ? (u32)(2 * t + 1) : (u32)(2 * t);
  __syncthreads();

  // ---- compact ----
  const u32 B = sB;
  float c[4] = {x.x, x.y, x.z, x.w};
  u32 win = 0;
#pragma unroll
  for (int j = 0; j < 4; ++j)
    if (c[j] > 0.0f && bucket_of(c[j]) >= B) win |= 1u << j;
  u32 wpos[4], wcnt[4];
#pragma unroll
  for (int j = 0; j < 4; ++j) {               // wave-uniform ballots
    u64 bal = __ballot((win >> j) & 1u);
    wcnt[j] = (u32)__popcll(bal);
    wpos[j] = (u32)__popcll(bal & ((1ull << lane) - 1ull));
  }
  if (lane == 0) {
#pragma unroll
    for (int j = 0; j < 4; ++j) cnt16[wave * 4 + j] = wcnt[j];
  }
  __syncthreads();
  if (t == 0) {                               // ONE device-atomic RMW per block
    u32 tot = 0, pre[16];
#pragma unroll
    for (int k = 0; k < 16; ++k) { pre[k] = tot; tot += cnt16[k]; }
#pragma unroll
    for (int k = 0; k < 16; ++k) cnt16[k] = pre[k];
    sBase = tot ? atomicAdd(&meta[MI_CNT], tot) : 0u;
  }
  __syncthreads();
#pragma unroll
  for (int j = 0; j < 4; ++j) {
    if ((win >> j) & 1u) {
      u32 dst = sBase + cnt16[wave * 4 + j] + wpos[j];
      if (dst < LIST_CAP) {
        u32 idx = (u32)(v * 4 + j);
        list[dst] = ((u64)__float_as_uint(c[j]) << 32) | (u64)(~idx);
      }
    }
  }
}

// K5: 63 blocks: exact rank (8 key-slices per candidate) + decode -> out.
__global__ void __launch_bounds__(256) k5_rank(
    const u32* __restrict__ meta, const u64* __restrict__ list,
    const float* __restrict__ bb8,  const float* __restrict__ kp8,
    const float* __restrict__ bb16, const float* __restrict__ kp16,
    const float* __restrict__ bb32, const float* __restrict__ kp32,
    float* __restrict__ out) {
  __shared__ __align__(16) u64 keys[LIST_CAP];
  __shared__ u32 rpart[256];
  __shared__ u32 sCnt;
  const int t = threadIdx.x, blk = blockIdx.x;
  if (t == 0) { u32 cc = meta[MI_CNT]; sCnt = cc > LIST_CAP ? LIST_CAP : cc; }
  __syncthreads();
  const u32 cnt = sCnt;
  for (int j = t; j < LIST_CAP; j += 256) keys[j] = (j < (int)cnt) ? list[j] : 0ull;
  __syncthreads();
  {
    const int ci = t & 31, sl = t >> 5;       // candidate-in-block, key-slice
    const int c = blk * CPB + ci;
    const int chunk = ((int)cnt + 7) >> 3;
    int lo = sl * chunk; if (lo > (int)cnt) lo = (int)cnt;
    int hi = lo + chunk; if (hi > (int)cnt) hi = (int)cnt;
    u64 my = keys[c];
    int r = 0, j = lo;
    for (; j + 4 <= hi; j += 4)
      r += (keys[j] > my) + (keys[j + 1] > my) + (keys[j + 2] > my) + (keys[j + 3] > my);
    for (; j < hi; ++j) r += (keys[j] > my);
    rpart[t] = (u32)r;
  }
  __syncthreads();
  if (t < CPB) {
    const int c = blk * CPB + t;
    if (c < (int)cnt) {
      int rank = 0;
#pragma unroll
      for (int q = 0; q < 8; ++q) rank += (int)rpart[t + 32 * q];
      if (rank < TOPK) {
        u64 my = keys[c];
        float lx = __uint_as_float((u32)(my >> 32));
        float sc = (float)(1.0 / (1.0 + exp(-(double)lx)));   // f64 sigmoid, round once
        u32 idx = ~((u32)my);
        float4 box;
        float kv[10];
        int p, xq, yq;
        float st;
        const float *bb, *kp;
        if (idx < N8) {
          st = 8.f;  p = (int)idx;              xq = p % 480; yq = p / 480; bb = bb8;  kp = kp8;
        } else if (idx < N8 + N16) {
          st = 16.f; p = (int)idx - N8;         xq = p % 240; yq = p / 240; bb = bb16; kp = kp16;
        } else {
          st = 32.f; p = (int)idx - (N8 + N16); xq = p % 120; yq = p / 120; bb = bb32; kp = kp32;
        }
        float cx = (float)xq * st, cy = (float)yq * st;
        {
#pragma clang fp contract(off)
          float d0 = bb[4 * p + 0] * st;
          float d1 = bb[4 * p + 1] * st;
          float d2 = bb[4 * p + 2] * st;
          float d3 = bb[4 * p + 3] * st;
          box.x = cx - d0; box.y = cy - d1; box.z = cx + d2; box.w = cy + d3;
          for (int q = 0; q < 10; ++q)
            kv[q] = kp[10 * p + q] * st + ((q & 1) ? cy : cx);
        }
        ((float4*)out)[rank] = box;
        out[4000 + rank] = sc;
#pragma unroll
        for (int q = 0; q < 10; ++q) out[5000 + 10 * rank + q] = kv[q];
      }
    } else if (c < TOPK) {        // unfilled rows: zero
      ((float4*)out)[c] = make_float4(0.f, 0.f, 0.f, 0.f);
      out[4000 + c] = 0.f;
#pragma unroll
      for (int q = 0; q < 10; ++q) out[5000 + 10 * c + q] = 0.f;
    }
  }
}

// K67: suppression bitmask (63 blocks, sc1 stores) + last-arriver greedy NMS.
__global__ void __launch_bounds__(256) k67_iou_nms(
    u32* meta, u64* nzWords, u64* mask, float* out) {
  __shared__ __align__(16) char smem[36864];
  __shared__ int isLast;
  __shared__ u32 sPc[16], sOff17[17];
  __shared__ u64 sRem[NWORDS];
  const int t = threadIdx.x, blk = blockIdx.x;

  float4* boxes = (float4*)smem;
  for (int r = t; r < TOPK; r += 256) boxes[r] = ((const float4*)out)[r];
  __syncthreads();
  int task = blk * 256 + t;
  if (task < IOU_TASKS) {
    int w = task / 1000;          // 0..15  (wave-mostly-uniform)
    int i = task - w * 1000;      // 0..999 (consecutive per lane -> coalesced)
    float4 a = boxes[i];
    int bse = w * 64;
    int jend = (bse + 64) < TOPK ? (bse + 64) : TOPK;
    u64 bits = 0;
    for (int j = bse; j < jend; ++j)          // boxes[j] wave-broadcast
      if (j > i && iou_gt04(a, boxes[j])) bits |= 1ull << (j - bse);
    ast64(&mask[(u64)w * 1000 + i], bits);    // sc1: visible to the last arriver
    if (bits) atomicOr(&nzWords[i >> 6], 1ull << (i & 63));
  }
  __syncthreads();                // drain sc1 mask stores + atomics (vmcnt)
  if (t == 0)
    isLast = (__hip_atomic_fetch_add(&meta[MI_IOU], 1u, __ATOMIC_RELAXED,
                                     __HIP_MEMORY_SCOPE_AGENT) == (u32)(IOU_BLKS - 1));
  __syncthreads();
  if (!isLast) return;

  // ---- last arriver: exact greedy NMS over nonzero-mask rows only ----
  u32 cc = meta[MI_CNT];
  if (cc > LIST_CAP) cc = LIST_CAP;
  const u32 vcnt = cc < TOPK ? cc : TOPK;
  u32* rows = (u32*)smem;               // up to 1000 row ids (4 KB)
  u64* cache = (u64*)(smem + 4096);     // NMS_CACHE x 16 u64 (32 KB)
  u64 nzv = 0;
  if (t < NWORDS) {
    nzv = ald64(&nzWords[t]) & valid_word(t, vcnt);
    sPc[t] = (u32)__popcll(nzv);
  }
  __syncthreads();
  if (t == 0) {
    u32 o = 0;
    for (int w = 0; w < NWORDS; ++w) { sOff17[w] = o; o += sPc[w]; }
    sOff17[16] = o;
  }
  __syncthreads();
  if (t < NWORDS) {                     // expand to ascending row list
    u64 m = nzv;
    u32 o = sOff17[t];
    while (m) { int b = __builtin_ctzll(m); m &= m - 1; rows[o++] = (u32)(t * 64 + b); }
  }
  __syncthreads();
  const int S = (int)sOff17[16];
  const int Sc = S < NMS_CACHE ? S : NMS_CACHE;
  for (int idx = t; idx < Sc * NWORDS; idx += 256) {   // parallel mask prefetch
    int s = idx >> 4, w = idx & 15;
    cache[s * NWORDS + w] = ald64(&mask[(u64)w * 1000 + rows[s]]);
  }
  __syncthreads();
  if (t < 64) {                 // serial greedy chain; lane<16 owns word `lane`
    u64 remv = 0;
    for (int s = 0; s < S; ++s) {
      u32 row = rows[s];
      int c = (int)(row >> 6), b = (int)(row & 63);
      u64 remc = __shfl(remv, c);
      if (!((remc >> b) & 1ull)) {     // row alive -> apply its suppression row
        u64 m = 0;
        if (t < NWORDS)
          m = (s < NMS_CACHE) ? cache[s * NWORDS + t] : ald64(&mask[(u64)t * 1000 + row]);
        remv |= m;
      }
    }
    if (t < NWORDS) sRem[t] = valid_word(t, vcnt) & remv;
  }
  __syncthreads();
  for (int r = t; r < TOPK; r += 256) {
    if ((sRem[r >> 6] >> (r & 63)) & 1ull) {
      ((float4*)out)[r] = make_float4(0.f, 0.f, 0.f, 0.f);
      out[4000 + r] = 0.f;
#pragma unroll
      for (int q = 0; q < 10; ++q) out[5000 + 10 * r + q] = 0.f;
    }
  }
}

extern "C" void kernel_launch(void* const* d_in, const int* in_sizes, int n_in,
                              void* d_out, int out_size, void* d_ws, size_t ws_size,
                              hipStream_t stream) {
  const float* s8   = (const float*)d_in[1];
  const float* bb8  = (const float*)d_in[2];
  const float* kp8  = (const float*)d_in[3];
  const float* s16  = (const float*)d_in[4];
  const float* bb16 = (const float*)d_in[5];
  const float* kp16 = (const float*)d_in[6];
  const float* s32  = (const float*)d_in[7];
  const float* bb32 = (const float*)d_in[8];
  const float* kp32 = (const float*)d_in[9];

  char* ws = (char*)d_ws;
  u32* part    = (u32*)(ws + OFF_PART);
  u32* meta    = (u32*)(ws + OFF_META);
  u64* nzWords = (u64*)(ws + OFF_NZ);
  u64* list    = (u64*)(ws + OFF_LIST);
  u64* mask    = (u64*)(ws + OFF_MASK);
  float* out   = (float*)d_out;

  k1_hist<<<HIST_BLKS, HIST_THR, 0, stream>>>(s8, s16, s32, part, meta, nzWords);
  k4_compact<<<CMP_BLKS, 256, 0, stream>>>(s8, s16, s32, part, meta, list);
  k5_rank<<<RANK_BLKS, 256, 0, stream>>>(meta, list, bb8, kp8, bb16, kp16, bb32, kp32, out);
  k67_iou_nms<<<IOU_BLKS, 256, 0, stream>>>(meta, nzWords, mask, out);
}

// Round 12
// 166.813 us; speedup vs baseline: 1.2470x; 1.0032x over previous
//
#include <hip/hip_runtime.h>
#include <stdint.h>

typedef unsigned int u32;
typedef unsigned long long u64;

#define N8   130560   // (2176/8)*(3840/8)   = 272*480
#define N16  32640    // (2176/16)*(3840/16) = 136*240
#define N32  8160     // (2176/32)*(3840/32) = 68*120
#define NTOT 171360
#define NTOT4 42840   // NTOT/4
#define TOPK 1000
#define NWORDS 16
#define NBINS 512
#define BUCKET_SCALE 85.25f
#define LIST_CAP 2016      // 63*32
#define CPB 32             // candidates ranked per block
#define HIST_BLKS 84       // 84*512 threads = 43008 >= NTOT4
#define HIST_THR 512
#define CMP_BLKS 168       // ceil(NTOT4/256)
#define RANK_BLKS 63
#define IOU_BLKS 63
#define IOU_TASKS (TOPK * NWORDS)   // 16000
#define NMS_CACHE 256

// R20 (FINAL): exact revert to R17 — the best measured configuration (166.59us).
// R19's 42x1024 hist trim was noise-neutral (+0.7us); terminate on the verified
// best. Session conclusion: the structure is at a launch-latency/harness floor,
// NOT a HW roofline (our kernels: <1% HBM, <5% VALU; timed window dominated by
// harness fill/copy at 85% HBM peak). Validated design rules from this session:
// - dispatch boundaries ~3.5us; spin fabric costs far more (R11: 60.9us kernel,
//   99% waiting) -> no-spin multi-dispatch beats fusion;
// - redundant parallel work beats serialized tails (R14/R17 findB; R15/R16 anti);
// - never relocate work into low-occupancy blocks without eval-count arithmetic
//   (R18: +41us); global-atomic histograms on hot bins serialize at IF (R12);
// - last-arriver (arrive-and-exit) is the one cheap same-dispatch handoff.

#define MI_CNT 0       // line 0: k4 list-count RMW (zeroed by k1 blk0)
#define MI_IOU 128     // line 1: k67 arrive ctr   (zeroed by k1 blk0)
#define META_U32 256

// workspace layout (bytes)
#define OFF_PART 0                  // u32[84*256] u16-pair packed partial hist
#define OFF_META 86016              // u32[256]
#define OFF_NZ   87040              // u64[16]
#define OFF_LIST 87168              // u64[2016]
#define OFF_MASK 103296             // u64[16*1000] transposed: mask[w*1000+i]

__device__ __forceinline__ u64 ald64(const u64* p) {
  return __hip_atomic_load(p, __ATOMIC_RELAXED, __HIP_MEMORY_SCOPE_AGENT);
}
__device__ __forceinline__ void ast64(u64* p, u64 v) {
  __hip_atomic_store(p, v, __ATOMIC_RELAXED, __HIP_MEMORY_SCOPE_AGENT);
}

__device__ __forceinline__ u32 bucket_of(float x) {
  u32 b = (u32)(x * BUCKET_SCALE);
  return b > (NBINS - 1) ? (NBINS - 1) : b;
}

__device__ __forceinline__ float4 load_logit4(int v, const float* s8, const float* s16,
                                              const float* s32) {
  int e = v * 4;
  if (e < N8) return ((const float4*)s8)[v];
  if (e < N8 + N16) return ((const float4*)s16)[v - N8 / 4];
  return ((const float4*)s32)[v - (N8 + N16) / 4];
}

__device__ __forceinline__ bool iou_gt04(float4 a, float4 b) {
#pragma clang fp contract(off)
  float areaA = (a.z - a.x) * (a.w - a.y);
  float areaB = (b.z - b.x) * (b.w - b.y);
  float ltx = fmaxf(a.x, b.x);
  float lty = fmaxf(a.y, b.y);
  float rbx = fminf(a.z, b.z);
  float rby = fminf(a.w, b.w);
  float wx = rbx - ltx; wx = wx > 0.0f ? wx : 0.0f;
  float wy = rby - lty; wy = wy > 0.0f ? wy : 0.0f;
  float inter = wx * wy;
  float un = areaA + areaB - inter;
  un = un > 1e-9f ? un : 1e-9f;
  return (inter / un) > 0.4f;
}

__device__ __forceinline__ u64 valid_word(int w, u32 vcnt) {
  int lo = w * 64;
  if ((int)vcnt >= lo + 64) return ~0ull;
  if ((int)vcnt <= lo) return 0ull;
  return (1ull << (vcnt - (u32)lo)) - 1ull;
}

// K1: pure histogram. 84x512, LDS 512-bin hist -> u16-packed partial (PLAIN
// stores; dispatch boundary provides coherence). blk0 zeroes meta + nz.
__global__ void __launch_bounds__(HIST_THR) k1_hist(
    const float* __restrict__ s8, const float* __restrict__ s16, const float* __restrict__ s32,
    u32* __restrict__ part, u32* __restrict__ meta, u64* __restrict__ nz) {
  __shared__ u32 lh[NBINS];
  const int t = threadIdx.x, blk = blockIdx.x;
  if (t < NBINS) lh[t] = 0;       // HIST_THR == 512 == NBINS
  __syncthreads();
  int v = blk * HIST_THR + t;
  if (v < NTOT4) {
    float4 x = load_logit4(v, s8, s16, s32);
    if (x.x > 0.0f) atomicAdd(&lh[bucket_of(x.x)], 1u);
    if (x.y > 0.0f) atomicAdd(&lh[bucket_of(x.y)], 1u);
    if (x.z > 0.0f) atomicAdd(&lh[bucket_of(x.z)], 1u);
    if (x.w > 0.0f) atomicAdd(&lh[bucket_of(x.w)], 1u);
  }
  __syncthreads();
  if (t < 256)                    // per-block bin count <= 2048 -> u16 ok
    part[blk * 256 + t] = lh[2 * t] | (lh[2 * t + 1] << 16);
  if (blk == 0) {
    if (t < META_U32) meta[t] = 0;
    if (t < NWORDS) nz[t] = 0ull;
  }
}

// K4: every block: redundant parallel findB (reduce 84 partials + 256-word scan)
// then block-aggregated compaction. Plain cached loads; one atomicAdd per block.
__global__ void __launch_bounds__(256) k4_compact(
    const float* __restrict__ s8, const float* __restrict__ s16, const float* __restrict__ s32,
    const u32* __restrict__ part, u32* __restrict__ meta, u64* __restrict__ list) {
  __shared__ u32 csum[256];
  __shared__ u32 sB, sBase;
  __shared__ u32 cnt16[16];
  const int t = threadIdx.x, blk = blockIdx.x;
  const int wave = t >> 6, lane = t & 63;
  const int v = blk * 256 + t;
  // prefetch scores early (latency overlap with the reduce below)
  float4 x = make_float4(-1.f, -1.f, -1.f, -1.f);
  if (v < NTOT4) x = load_logit4(v, s8, s16, s32);

  // ---- redundant findB: thread t owns packed word t (bins 2t, 2t+1) ----
  u32 lo = 0, hi = 0;
  {
    int p = 0;
    for (; p + 4 <= HIST_BLKS; p += 4) {    // coalesced across threads at each p
      u32 a0 = part[(p + 0) * 256 + t];
      u32 a1 = part[(p + 1) * 256 + t];
      u32 a2 = part[(p + 2) * 256 + t];
      u32 a3 = part[(p + 3) * 256 + t];
      lo += (a0 & 0xFFFFu) + (a1 & 0xFFFFu) + (a2 & 0xFFFFu) + (a3 & 0xFFFFu);
      hi += (a0 >> 16) + (a1 >> 16) + (a2 >> 16) + (a3 >> 16);
    }
    for (; p < HIST_BLKS; ++p) {
      u32 a = part[p * 256 + t];
      lo += a & 0xFFFFu; hi += a >> 16;
    }
  }
  csum[t] = lo + hi;
  __syncthreads();
  for (int off = 1; off < 256; off <<= 1) {   // inclusive suffix scan over words
    u32 add = (t + off < 256) ? csum[t + off] : 0u;
    __syncthreads();
    csum[t] += add;
    __syncthreads();
  }
  u32 above = (t < 255) ? csum[t + 1] : 0u;
  if (t == 0 && csum[0] < TOPK) sB = 0u;      // fewer than TOPK positives
  if (csum[t] >= TOPK && above < TOPK)        // exactly one thread
    sB = (above + hi >= TOPK) ? (u32)(2 * t + 1) : (u32)(2 * t);
  __syncthreads();

  // ---- compact ----
  const u32 B = sB;
  float c[4] = {x.x, x.y, x.z, x.w};
  u32 win = 0;
#pragma unroll
  for (int j = 0; j < 4; ++j)
    if (c[j] > 0.0f && bucket_of(c[j]) >= B) win |= 1u << j;
  u32 wpos[4], wcnt[4];
#pragma unroll
  for (int j = 0; j < 4; ++j) {               // wave-uniform ballots
    u64 bal = __ballot((win >> j) & 1u);
    wcnt[j] = (u32)__popcll(bal);
    wpos[j] = (u32)__popcll(bal & ((1ull << lane) - 1ull));
  }
  if (lane == 0) {
#pragma unroll
    for (int j = 0; j < 4; ++j) cnt16[wave * 4 + j] = wcnt[j];
  }
  __syncthreads();
  if (t == 0) {                               // ONE device-atomic RMW per block
    u32 tot = 0, pre[16];
#pragma unroll
    for (int k = 0; k < 16; ++k) { pre[k] = tot; tot += cnt16[k]; }
#pragma unroll
    for (int k = 0; k < 16; ++k) cnt16[k] = pre[k];
    sBase = tot ? atomicAdd(&meta[MI_CNT], tot) : 0u;
  }
  __syncthreads();
#pragma unroll
  for (int j = 0; j < 4; ++j) {
    if ((win >> j) & 1u) {
      u32 dst = sBase + cnt16[wave * 4 + j] + wpos[j];
      if (dst < LIST_CAP) {
        u32 idx = (u32)(v * 4 + j);
        list[dst] = ((u64)__float_as_uint(c[j]) << 32) | (u64)(~idx);
      }
    }
  }
}

// K5: 63 blocks: exact rank (8 key-slices per candidate) + decode -> out.
__global__ void __launch_bounds__(256) k5_rank(
    const u32* __restrict__ meta, const u64* __restrict__ list,
    const float* __restrict__ bb8,  const float* __restrict__ kp8,
    const float* __restrict__ bb16, const float* __restrict__ kp16,
    const float* __restrict__ bb32, const float* __restrict__ kp32,
    float* __restrict__ out) {
  __shared__ __align__(16) u64 keys[LIST_CAP];
  __shared__ u32 rpart[256];
  __shared__ u32 sCnt;
  const int t = threadIdx.x, blk = blockIdx.x;
  if (t == 0) { u32 cc = meta[MI_CNT]; sCnt = cc > LIST_CAP ? LIST_CAP : cc; }
  __syncthreads();
  const u32 cnt = sCnt;
  for (int j = t; j < LIST_CAP; j += 256) keys[j] = (j < (int)cnt) ? list[j] : 0ull;
  __syncthreads();
  {
    const int ci = t & 31, sl = t >> 5;       // candidate-in-block, key-slice
    const int c = blk * CPB + ci;
    const int chunk = ((int)cnt + 7) >> 3;
    int lo = sl * chunk; if (lo > (int)cnt) lo = (int)cnt;
    int hi = lo + chunk; if (hi > (int)cnt) hi = (int)cnt;
    u64 my = keys[c];
    int r = 0, j = lo;
    for (; j + 4 <= hi; j += 4)
      r += (keys[j] > my) + (keys[j + 1] > my) + (keys[j + 2] > my) + (keys[j + 3] > my);
    for (; j < hi; ++j) r += (keys[j] > my);
    rpart[t] = (u32)r;
  }
  __syncthreads();
  if (t < CPB) {
    const int c = blk * CPB + t;
    if (c < (int)cnt) {
      int rank = 0;
#pragma unroll
      for (int q = 0; q < 8; ++q) rank += (int)rpart[t + 32 * q];
      if (rank < TOPK) {
        u64 my = keys[c];
        float lx = __uint_as_float((u32)(my >> 32));
        float sc = (float)(1.0 / (1.0 + exp(-(double)lx)));   // f64 sigmoid, round once
        u32 idx = ~((u32)my);
        float4 box;
        float kv[10];
        int p, xq, yq;
        float st;
        const float *bb, *kp;
        if (idx < N8) {
          st = 8.f;  p = (int)idx;              xq = p % 480; yq = p / 480; bb = bb8;  kp = kp8;
        } else if (idx < N8 + N16) {
          st = 16.f; p = (int)idx - N8;         xq = p % 240; yq = p / 240; bb = bb16; kp = kp16;
        } else {
          st = 32.f; p = (int)idx - (N8 + N16); xq = p % 120; yq = p / 120; bb = bb32; kp = kp32;
        }
        float cx = (float)xq * st, cy = (float)yq * st;
        {
#pragma clang fp contract(off)
          float d0 = bb[4 * p + 0] * st;
          float d1 = bb[4 * p + 1] * st;
          float d2 = bb[4 * p + 2] * st;
          float d3 = bb[4 * p + 3] * st;
          box.x = cx - d0; box.y = cy - d1; box.z = cx + d2; box.w = cy + d3;
          for (int q = 0; q < 10; ++q)
            kv[q] = kp[10 * p + q] * st + ((q & 1) ? cy : cx);
        }
        ((float4*)out)[rank] = box;
        out[4000 + rank] = sc;
#pragma unroll
        for (int q = 0; q < 10; ++q) out[5000 + 10 * rank + q] = kv[q];
      }
    } else if (c < TOPK) {        // unfilled rows: zero
      ((float4*)out)[c] = make_float4(0.f, 0.f, 0.f, 0.f);
      out[4000 + c] = 0.f;
#pragma unroll
      for (int q = 0; q < 10; ++q) out[5000 + 10 * c + q] = 0.f;
    }
  }
}

// K67: suppression bitmask (63 blocks, sc1 stores) + last-arriver greedy NMS.
__global__ void __launch_bounds__(256) k67_iou_nms(
    u32* meta, u64* nzWords, u64* mask, float* out) {
  __shared__ __align__(16) char smem[36864];
  __shared__ int isLast;
  __shared__ u32 sPc[16], sOff17[17];
  __shared__ u64 sRem[NWORDS];
  const int t = threadIdx.x, blk = blockIdx.x;

  float4* boxes = (float4*)smem;
  for (int r = t; r < TOPK; r += 256) boxes[r] = ((const float4*)out)[r];
  __syncthreads();
  int task = blk * 256 + t;
  if (task < IOU_TASKS) {
    int w = task / 1000;          // 0..15  (wave-mostly-uniform)
    int i = task - w * 1000;      // 0..999 (consecutive per lane -> coalesced)
    float4 a = boxes[i];
    int bse = w * 64;
    int jend = (bse + 64) < TOPK ? (bse + 64) : TOPK;
    u64 bits = 0;
    for (int j = bse; j < jend; ++j)          // boxes[j] wave-broadcast
      if (j > i && iou_gt04(a, boxes[j])) bits |= 1ull << (j - bse);
    ast64(&mask[(u64)w * 1000 + i], bits);    // sc1: visible to the last arriver
    if (bits) atomicOr(&nzWords[i >> 6], 1ull << (i & 63));
  }
  __syncthreads();                // drain sc1 mask stores + atomics (vmcnt)
  if (t == 0)
    isLast = (__hip_atomic_fetch_add(&meta[MI_IOU], 1u, __ATOMIC_RELAXED,
                                     __HIP_MEMORY_SCOPE_AGENT) == (u32)(IOU_BLKS - 1));
  __syncthreads();
  if (!isLast) return;

  // ---- last arriver: exact greedy NMS over nonzero-mask rows only ----
  u32 cc = meta[MI_CNT];
  if (cc > LIST_CAP) cc = LIST_CAP;
  const u32 vcnt = cc < TOPK ? cc : TOPK;
  u32* rows = (u32*)smem;               // up to 1000 row ids (4 KB)
  u64* cache = (u64*)(smem + 4096);     // NMS_CACHE x 16 u64 (32 KB)
  u64 nzv = 0;
  if (t < NWORDS) {
    nzv = ald64(&nzWords[t]) & valid_word(t, vcnt);
    sPc[t] = (u32)__popcll(nzv);
  }
  __syncthreads();
  if (t == 0) {
    u32 o = 0;
    for (int w = 0; w < NWORDS; ++w) { sOff17[w] = o; o += sPc[w]; }
    sOff17[16] = o;
  }
  __syncthreads();
  if (t < NWORDS) {                     // expand to ascending row list
    u64 m = nzv;
    u32 o = sOff17[t];
    while (m) { int b = __builtin_ctzll(m); m &= m - 1; rows[o++] = (u32)(t * 64 + b); }
  }
  __syncthreads();
  const int S = (int)sOff17[16];
  const int Sc = S < NMS_CACHE ? S : NMS_CACHE;
  for (int idx = t; idx < Sc * NWORDS; idx += 256) {   // parallel mask prefetch
    int s = idx >> 4, w = idx & 15;
    cache[s * NWORDS + w] = ald64(&mask[(u64)w * 1000 + rows[s]]);
  }
  __syncthreads();
  if (t < 64) {                 // serial greedy chain; lane<16 owns word `lane`
    u64 remv = 0;
    for (int s = 0; s < S; ++s) {
      u32 row = rows[s];
      int c = (int)(row >> 6), b = (int)(row & 63);
      u64 remc = __shfl(remv, c);
      if (!((remc >> b) & 1ull)) {     // row alive -> apply its suppression row
        u64 m = 0;
        if (t < NWORDS)
          m = (s < NMS_CACHE) ? cache[s * NWORDS + t] : ald64(&mask[(u64)t * 1000 + row]);
        remv |= m;
      }
    }
    if (t < NWORDS) sRem[t] = valid_word(t, vcnt) & remv;
  }
  __syncthreads();
  for (int r = t; r < TOPK; r += 256) {
    if ((sRem[r >> 6] >> (r & 63)) & 1ull) {
      ((float4*)out)[r] = make_float4(0.f, 0.f, 0.f, 0.f);
      out[4000 + r] = 0.f;
#pragma unroll
      for (int q = 0; q < 10; ++q) out[5000 + 10 * r + q] = 0.f;
    }
  }
}

extern "C" void kernel_launch(void* const* d_in, const int* in_sizes, int n_in,
                              void* d_out, int out_size, void* d_ws, size_t ws_size,
                              hipStream_t stream) {
  const float* s8   = (const float*)d_in[1];
  const float* bb8  = (const float*)d_in[2];
  const float* kp8  = (const float*)d_in[3];
  const float* s16  = (const float*)d_in[4];
  const float* bb16 = (const float*)d_in[5];
  const float* kp16 = (const float*)d_in[6];
  const float* s32  = (const float*)d_in[7];
  const float* bb32 = (const float*)d_in[8];
  const float* kp32 = (const float*)d_in[9];

  char* ws = (char*)d_ws;
  u32* part    = (u32*)(ws + OFF_PART);
  u32* meta    = (u32*)(ws + OFF_META);
  u64* nzWords = (u64*)(ws + OFF_NZ);
  u64* list    = (u64*)(ws + OFF_LIST);
  u64* mask    = (u64*)(ws + OFF_MASK);
  float* out   = (float*)d_out;

  k1_hist<<<HIST_BLKS, HIST_THR, 0, stream>>>(s8, s16, s32, part, meta, nzWords);
  k4_compact<<<CMP_BLKS, 256, 0, stream>>>(s8, s16, s32, part, meta, list);
  k5_rank<<<RANK_BLKS, 256, 0, stream>>>(meta, list, bb8, kp8, bb16, kp16, bb32, kp32, out);
  k67_iou_nms<<<IOU_BLKS, 256, 0, stream>>>(meta, nzWords, mask, out);
}